// Round 1
// 1301.631 us; speedup vs baseline: 1.1210x; 1.1210x over previous
//
#include <hip/hip_runtime.h>
#include <cmath>

typedef _Float16 f16;
typedef _Float16 half8 __attribute__((ext_vector_type(8)));
typedef _Float16 half4 __attribute__((ext_vector_type(4)));
typedef float f32x4 __attribute__((ext_vector_type(4)));

__device__ __forceinline__ void atomAddF(float* p, float v) { unsafeAtomicAdd(p, v); }

// async global->LDS, 16B per lane. LDS dest must be wave-uniform base + lane*16 (linear).
__device__ __forceinline__ void gload16(const void* g, void* l) {
    __builtin_amdgcn_global_load_lds((const __attribute__((address_space(1))) void*)g,
                                     (__attribute__((address_space(3))) void*)l, 16, 0, 0);
}

// ---------------- merged setup: all weight transposes + zero all degree counters ----------------
// regions: [0,32768): c0_w1 (128x256) -> w1t0 (256x128 f16)
//          [32768, 32768+6*65536): 6 matrices 256x256 -> f16 transposed
//          then lin2 (256x47 -> 47x256 f32), then deg zero (136192 ints)
struct SetupP {
    const float* ws[7];
    f16* wd[7];
    const float* l2s;
    float* l2d;
    int* deg;
};

__global__ void setup_all(SetupP p) {
    int i = blockIdx.x * 256 + threadIdx.x;
    if (i < 32768) {
        int k = i >> 8, n = i & 255;
        p.wd[0][(size_t)n * 128 + k] = (f16)p.ws[0][i];
        return;
    }
    i -= 32768;
    if (i < 6 * 65536) {
        int m = i >> 16, r = i & 65535;
        int k = r >> 8, n = r & 255;
        p.wd[1 + m][(size_t)n * 256 + k] = (f16)p.ws[1 + m][r];
        return;
    }
    i -= 6 * 65536;
    if (i < 12032) {
        int k = i / 47, j = i - k * 47;
        p.l2d[(size_t)j * 256 + k] = p.l2s[i];
        return;
    }
    i -= 12032;
    if (i < 136192) p.deg[i] = 0;
}

__global__ void zero_stats(float* p) { p[blockIdx.x * 256 + threadIdx.x] = 0.f; }

// ---------------- adjacency build, all 3 layers in one dispatch ----------------
// deg arena: [0,123904) L0, [123904,135168) L1, [135168,136192) L2; adj arena row-capacity 64.
__global__ void fill_all(const int* __restrict__ e0, const int* __restrict__ e1,
                         const int* __restrict__ e2, int E0, int E1, int E2, int* __restrict__ deg,
                         int* __restrict__ adj) {
    int e = blockIdx.x * 256 + threadIdx.x;
    const int *src, *tgt;
    int* d;
    int* a;
    if (e < E0) {
        src = e0; tgt = e0 + E0; d = deg; a = adj;
    } else if (e < E0 + E1) {
        e -= E0;
        src = e1; tgt = e1 + E1; d = deg + 123904; a = adj + (size_t)123904 * 64;
    } else if (e < E0 + E1 + E2) {
        e -= E0 + E1;
        src = e2; tgt = e2 + E2; d = deg + 135168; a = adj + (size_t)135168 * 64;
    } else {
        return;
    }
    int t = tgt[e];
    int pos = atomicAdd(&d[t], 1);
    if (pos < 64) a[(size_t)t * 64 + pos] = src[e];
}

// ---------------- gather-based segment sum: h[t] = x[t] + sum_{s in adj[t]} x[s] ----------------
// 4x unrolled neighbor loop: 4 independent 512B row-loads in flight per wave.

__global__ void gather128(const float* __restrict__ x, const int* __restrict__ deg,
                          const int* __restrict__ adj, f16* __restrict__ h) {
    const int wave = threadIdx.x >> 6, lane = threadIdx.x & 63;
    const int row = blockIdx.x * 4 + wave;
    const int c = lane * 2;
    const float* xr = x + (size_t)row * 128 + c;
    float a0 = xr[0], a1 = xr[1];
    const int n = min(deg[row], 64);
    const int myadj = adj[(size_t)row * 64 + lane];
    int j = 0;
    for (; j + 4 <= n; j += 4) {
        int s0 = __shfl(myadj, j), s1 = __shfl(myadj, j + 1);
        int s2 = __shfl(myadj, j + 2), s3 = __shfl(myadj, j + 3);
        const float* p0 = x + (size_t)s0 * 128 + c;
        const float* p1 = x + (size_t)s1 * 128 + c;
        const float* p2 = x + (size_t)s2 * 128 + c;
        const float* p3 = x + (size_t)s3 * 128 + c;
        float b00 = p0[0], b01 = p0[1], b10 = p1[0], b11 = p1[1];
        float b20 = p2[0], b21 = p2[1], b30 = p3[0], b31 = p3[1];
        a0 += (b00 + b10) + (b20 + b30);
        a1 += (b01 + b11) + (b21 + b31);
    }
    for (; j < n; ++j) {
        int s = __shfl(myadj, j);
        const float* p = x + (size_t)s * 128 + c;
        a0 += p[0];
        a1 += p[1];
    }
    f16* hp = h + (size_t)row * 128 + c;
    hp[0] = (f16)a0;
    hp[1] = (f16)a1;
}

__global__ void gather256(const f16* __restrict__ x, const int* __restrict__ deg,
                          const int* __restrict__ adj, f16* __restrict__ h) {
    const int wave = threadIdx.x >> 6, lane = threadIdx.x & 63;
    const int row = blockIdx.x * 4 + wave;
    const int c = lane * 4;
    half4 xv = *(const half4*)(x + (size_t)row * 256 + c);
    float a0 = (float)xv[0], a1 = (float)xv[1], a2 = (float)xv[2], a3 = (float)xv[3];
    const int n = min(deg[row], 64);
    const int myadj = adj[(size_t)row * 64 + lane];
    int j = 0;
    for (; j + 4 <= n; j += 4) {
        int s0 = __shfl(myadj, j), s1 = __shfl(myadj, j + 1);
        int s2 = __shfl(myadj, j + 2), s3 = __shfl(myadj, j + 3);
        half4 v0 = *(const half4*)(x + (size_t)s0 * 256 + c);
        half4 v1 = *(const half4*)(x + (size_t)s1 * 256 + c);
        half4 v2 = *(const half4*)(x + (size_t)s2 * 256 + c);
        half4 v3 = *(const half4*)(x + (size_t)s3 * 256 + c);
        a0 += ((float)v0[0] + (float)v1[0]) + ((float)v2[0] + (float)v3[0]);
        a1 += ((float)v0[1] + (float)v1[1]) + ((float)v2[1] + (float)v3[1]);
        a2 += ((float)v0[2] + (float)v1[2]) + ((float)v2[2] + (float)v3[2]);
        a3 += ((float)v0[3] + (float)v1[3]) + ((float)v2[3] + (float)v3[3]);
    }
    for (; j < n; ++j) {
        int s = __shfl(myadj, j);
        half4 v = *(const half4*)(x + (size_t)s * 256 + c);
        a0 += (float)v[0];
        a1 += (float)v[1];
        a2 += (float)v[2];
        a3 += (float)v[3];
    }
    half4 o;
    o[0] = (f16)a0;
    o[1] = (f16)a1;
    o[2] = (f16)a2;
    o[3] = (f16)a3;
    *(half4*)(h + (size_t)row * 256 + c) = o;
}

// ---------------- 128x128 GEMM, m97 structure: global_load_lds(16B) + chunk-XOR swizzle ------
// C(MxN f16) = A(MxK f16) @ Bt^T(NxK f16) + bias, opt relu. M%128==0, N%128==0, K%32==0.
// LDS tile [row][32 halves] linear; 16B chunk at (row,ch) holds global chunk ch^((row>>1)&3).
// Read side applies the same XOR -> ds_read_b128 is 2-way (free) instead of 8-way.
template <bool RELU>
__global__ __launch_bounds__(256) void gemm128(const f16* __restrict__ A, const f16* __restrict__ Bt,
                                               const float* __restrict__ bias, f16* __restrict__ C,
                                               int M, int N, int K) {
    __shared__ __attribute__((aligned(16))) f16 sA[128 * 32];
    __shared__ __attribute__((aligned(16))) f16 sB[128 * 32];
    const int tid = threadIdx.x;
    const int wave = tid >> 6, lane = tid & 63;
    const int quad = lane >> 4, l16 = lane & 15;
    const int wr = (wave & 1) * 64, wc = (wave >> 1) * 64;
    const int row0 = blockIdx.x * 128, col0 = blockIdx.y * 128;

    // staging: 2 x 16B per thread per matrix; LDS dest linear in tid, source chunk pre-swizzled
    const int i0 = tid, i1 = tid + 256;
    const int r0s = i0 >> 2, c0s = (i0 & 3) ^ ((r0s >> 1) & 3);
    const int r1s = i1 >> 2, c1s = (i1 & 3) ^ ((r1s >> 1) & 3);
    const f16* ga0 = A + (size_t)(row0 + r0s) * K + c0s * 8;
    const f16* ga1 = A + (size_t)(row0 + r1s) * K + c1s * 8;
    const f16* gb0 = Bt + (size_t)(col0 + r0s) * K + c0s * 8;
    const f16* gb1 = Bt + (size_t)(col0 + r1s) * K + c1s * 8;
    f16* la0 = &sA[i0 * 8];
    f16* la1 = &sA[i1 * 8];
    f16* lb0 = &sB[i0 * 8];
    f16* lb1 = &sB[i1 * 8];

    f32x4 acc[4][4] = {};

    for (int k0 = 0; k0 < K; k0 += 32) {
        __syncthreads();  // prior reads done before overwrite
        gload16(ga0 + k0, la0);
        gload16(ga1 + k0, la1);
        gload16(gb0 + k0, lb0);
        gload16(gb1 + k0, lb1);
        __syncthreads();  // drains vmcnt(0): staged tile visible
        half8 af[4], bf[4];
#pragma unroll
        for (int r = 0; r < 4; ++r) {
            const int ar = wr + r * 16 + l16;
            af[r] = *(const half8*)&sA[ar * 32 + ((quad ^ ((ar >> 1) & 3)) * 8)];
        }
#pragma unroll
        for (int c = 0; c < 4; ++c) {
            const int br = wc + c * 16 + l16;
            bf[c] = *(const half8*)&sB[br * 32 + ((quad ^ ((br >> 1) & 3)) * 8)];
        }
#pragma unroll
        for (int r = 0; r < 4; ++r)
#pragma unroll
            for (int c = 0; c < 4; ++c)
                acc[r][c] = __builtin_amdgcn_mfma_f32_16x16x32_f16(af[r], bf[c], acc[r][c], 0, 0, 0);
    }

    // epilogue: C/D layout col = lane&15, row = quad*4 + reg
#pragma unroll
    for (int c = 0; c < 4; ++c) {
        const int gcol = col0 + wc + c * 16 + l16;
        const float b = bias[gcol];
#pragma unroll
        for (int r = 0; r < 4; ++r) {
#pragma unroll
            for (int i = 0; i < 4; ++i) {
                const int grow = row0 + wr + r * 16 + quad * 4 + i;
                float v = acc[r][c][i] + b;
                if (RELU) v = fmaxf(v, 0.f);
                C[(size_t)grow * N + gcol] = (f16)v;
            }
        }
    }
}

// ---------------- 64x64 GEMM (kept for M=1024 shapes) ----------------
template <bool RELU>
__global__ __launch_bounds__(256) void gemm_bt(const f16* __restrict__ A, const f16* __restrict__ Bt,
                                               const float* __restrict__ bias, f16* __restrict__ C,
                                               int M, int N, int K) {
    constexpr int BM = 64, BN = 64, BK = 32, LP = 40;
    __shared__ f16 sA[BM * LP];
    __shared__ f16 sB[BN * LP];
    const int tid = threadIdx.x;
    const int wave = tid >> 6, lane = tid & 63;
    const int quad = lane >> 4, l16 = lane & 15;
    const int wr = (wave & 1) * 32, wc = (wave >> 1) * 32;
    const int row0 = blockIdx.x * BM, col0 = blockIdx.y * BN;
    const int srow = tid >> 2, soff = (tid & 3) * 8;

    f32x4 acc[2][2] = {};

    for (int k0 = 0; k0 < K; k0 += BK) {
        __syncthreads();
        *(half8*)&sA[srow * LP + soff] =
            *(const half8*)(A + (size_t)(row0 + srow) * K + (k0 + soff));
        *(half8*)&sB[srow * LP + soff] =
            *(const half8*)(Bt + (size_t)(col0 + srow) * K + (k0 + soff));
        __syncthreads();
        half8 af[2], bf[2];
#pragma unroll
        for (int r = 0; r < 2; ++r) af[r] = *(const half8*)&sA[(wr + r * 16 + l16) * LP + quad * 8];
#pragma unroll
        for (int c = 0; c < 2; ++c) bf[c] = *(const half8*)&sB[(wc + c * 16 + l16) * LP + quad * 8];
#pragma unroll
        for (int r = 0; r < 2; ++r)
#pragma unroll
            for (int c = 0; c < 2; ++c)
                acc[r][c] = __builtin_amdgcn_mfma_f32_16x16x32_f16(af[r], bf[c], acc[r][c], 0, 0, 0);
    }

#pragma unroll
    for (int c = 0; c < 2; ++c) {
        const int gcol = col0 + wc + c * 16 + l16;
        const float b = bias[gcol];
#pragma unroll
        for (int r = 0; r < 2; ++r) {
#pragma unroll
            for (int i = 0; i < 4; ++i) {
                const int grow = row0 + wr + r * 16 + quad * 4 + i;
                float v = acc[r][c][i] + b;
                if (RELU) v = fmaxf(v, 0.f);
                C[(size_t)grow * N + gcol] = (f16)v;
            }
        }
    }
}

// ---------------- BN ----------------

__global__ void colstats(const f16* __restrict__ h1, int nt, float* __restrict__ colsum,
                         float* __restrict__ colsumsq) {
    const int c = threadIdx.x;
    const int r0 = blockIdx.x * 128;
    const int rend = min(r0 + 128, nt);
    float s = 0.f, ss = 0.f;
    for (int r = r0; r < rend; ++r) {
        float v = (float)h1[(size_t)r * 256 + c];
        s += v;
        ss += v * v;
    }
    atomAddF(&colsum[c], s);
    atomAddF(&colsumsq[c], ss);
}

__global__ void bn_finalize(const float* __restrict__ colsum, const float* __restrict__ colsumsq,
                            const float* __restrict__ g, const float* __restrict__ be, float nt_inv,
                            float* __restrict__ scale, float* __restrict__ shift) {
    int c = threadIdx.x;
    float mu = colsum[c] * nt_inv;
    float var = colsumsq[c] * nt_inv - mu * mu;
    float sc = g[c] * rsqrtf(var + 1e-5f);
    scale[c] = sc;
    shift[c] = be[c] - mu * sc;
}

__global__ void bn_apply(f16* __restrict__ h, int total8, const float* __restrict__ scale,
                         const float* __restrict__ shift) {
    int i = blockIdx.x * 256 + threadIdx.x;
    if (i >= total8) return;
    size_t base = (size_t)i * 8;
    int c = (int)(base & 255);
    half8 v = *(half8*)(h + base);
#pragma unroll
    for (int j = 0; j < 8; ++j) {
        float f = (float)v[j] * scale[c + j] + shift[c + j];
        v[j] = (f16)fmaxf(f, 0.f);
    }
    *(half8*)(h + base) = v;
}

// ---------------- head: logits + log_softmax ----------------
__global__ void head2(const f16* __restrict__ T, const float* __restrict__ w2t,
                      const float* __restrict__ b2, float* __restrict__ out, int rows) {
    const int row = blockIdx.x;
    const int lane = threadIdx.x;
    __shared__ float tr[256];
    for (int i = lane; i < 256; i += 64) tr[i] = (float)T[(size_t)row * 256 + i];
    __syncthreads();
    float d = -1e30f;
    if (lane < 47) {
        const float* wr = w2t + (size_t)lane * 256;
        float dot = 0.f;
        for (int k = 0; k < 256; k += 4) {
            dot += tr[k] * wr[k] + tr[k + 1] * wr[k + 1] + tr[k + 2] * wr[k + 2] +
                   tr[k + 3] * wr[k + 3];
        }
        d = dot + b2[lane];
    }
    float m = d;
    for (int off = 32; off; off >>= 1) m = fmaxf(m, __shfl_xor(m, off));
    float e = (lane < 47) ? expf(d - m) : 0.f;
    float s = e;
    for (int off = 32; off; off >>= 1) s += __shfl_xor(s, off);
    if (lane < 47) out[(size_t)row * 47 + lane] = d - m - logf(s);
}

// ---------------- launch ----------------

extern "C" void kernel_launch(void* const* d_in, const int* in_sizes, int n_in, void* d_out,
                              int out_size, void* d_ws, size_t ws_size, hipStream_t stream) {
    const float* x0 = (const float*)d_in[0];
    const int* ei[3] = {(const int*)d_in[1], (const int*)d_in[2], (const int*)d_in[3]};
    const int E[3] = {in_sizes[1] / 2, in_sizes[2] / 2, in_sizes[3] / 2};
    const float* c_w1[3] = {(const float*)d_in[4], (const float*)d_in[10], (const float*)d_in[16]};
    const float* c_b1[3] = {(const float*)d_in[5], (const float*)d_in[11], (const float*)d_in[17]};
    const float* c_g[3] = {(const float*)d_in[6], (const float*)d_in[12], (const float*)d_in[18]};
    const float* c_be[3] = {(const float*)d_in[7], (const float*)d_in[13], (const float*)d_in[19]};
    const float* c_w2[3] = {(const float*)d_in[8], (const float*)d_in[14], (const float*)d_in[20]};
    const float* c_b2[3] = {(const float*)d_in[9], (const float*)d_in[15], (const float*)d_in[21]};
    const float* lin1_w = (const float*)d_in[22];
    const float* lin1_b = (const float*)d_in[23];
    const float* lin2_w = (const float*)d_in[24];
    const float* lin2_b = (const float*)d_in[25];
    float* out = (float*)d_out;

    const int NT[3] = {123904, 11264, 1024};

    char* base = (char*)d_ws;
    size_t off = 0;
    auto take = [&](size_t bytes) -> char* {
        char* p = base + off;
        off = (off + bytes + 255) & ~(size_t)255;
        return p;
    };
    f16* w1t[3];
    w1t[0] = (f16*)take((size_t)256 * 128 * sizeof(f16));
    w1t[1] = (f16*)take((size_t)256 * 256 * sizeof(f16));
    w1t[2] = (f16*)take((size_t)256 * 256 * sizeof(f16));
    f16* w2t[3];
    for (int i = 0; i < 3; ++i) w2t[i] = (f16*)take((size_t)256 * 256 * sizeof(f16));
    f16* lin1t = (f16*)take((size_t)256 * 256 * sizeof(f16));
    float* lin2t_ = (float*)take((size_t)47 * 256 * sizeof(float));
    float* stats = (float*)take(1024 * sizeof(float));
    int* deg = (int*)take((size_t)136192 * sizeof(int));
    int* adj = (int*)take((size_t)136192 * 64 * sizeof(int));
    f16* h0 = (f16*)take((size_t)123904 * 128 * sizeof(f16));  // also holds 11264x256, 1024x256
    f16* h1 = (f16*)take((size_t)123904 * 256 * sizeof(f16));
    f16* X1 = (f16*)take((size_t)123904 * 256 * sizeof(f16));
    f16* X2 = (f16*)take((size_t)11264 * 256 * sizeof(f16));
    f16* X3 = (f16*)take((size_t)1024 * 256 * sizeof(f16));
    f16* T = (f16*)take((size_t)1024 * 256 * sizeof(f16));
    (void)ws_size;
    (void)out_size;
    (void)n_in;

    int* deg_l[3] = {deg, deg + 123904, deg + 135168};
    int* adj_l[3] = {adj, adj + (size_t)123904 * 64, adj + (size_t)135168 * 64};

    // merged setup: weight transposes + deg zeroing (574208 work items)
    SetupP sp;
    sp.ws[0] = c_w1[0];
    sp.ws[1] = c_w1[1];
    sp.ws[2] = c_w1[2];
    sp.ws[3] = c_w2[0];
    sp.ws[4] = c_w2[1];
    sp.ws[5] = c_w2[2];
    sp.ws[6] = lin1_w;
    sp.wd[0] = w1t[0];
    sp.wd[1] = w1t[1];
    sp.wd[2] = w1t[2];
    sp.wd[3] = w2t[0];
    sp.wd[4] = w2t[1];
    sp.wd[5] = w2t[2];
    sp.wd[6] = lin1t;
    sp.l2s = lin2_w;
    sp.l2d = lin2t_;
    sp.deg = deg;
    setup_all<<<(574208 + 255) / 256, 256, 0, stream>>>(sp);

    // single adjacency build for all 3 layers
    fill_all<<<(E[0] + E[1] + E[2] + 255) / 256, 256, 0, stream>>>(ei[0], ei[1], ei[2], E[0], E[1],
                                                                  E[2], deg, adj);

    auto bn_mid = [&](const float* g, const float* be, int nt) {
        zero_stats<<<2, 256, 0, stream>>>(stats);
        colstats<<<(nt + 127) / 128, 256, 0, stream>>>(h1, nt, stats, stats + 256);
        bn_finalize<<<1, 256, 0, stream>>>(stats, stats + 256, g, be, 1.0f / nt, stats + 512,
                                           stats + 768);
        bn_apply<<<(nt * 256 / 8 + 255) / 256, 256, 0, stream>>>(h1, nt * 256 / 8, stats + 512,
                                                                 stats + 768);
    };

    // ---- layer 0 (x: fp32, din=128) ----
    gather128<<<NT[0] / 4, 256, 0, stream>>>(x0, deg_l[0], adj_l[0], h0);
    gemm128<false><<<dim3(NT[0] / 128, 2), 256, 0, stream>>>(h0, w1t[0], c_b1[0], h1, NT[0], 256,
                                                             128);
    bn_mid(c_g[0], c_be[0], NT[0]);
    gemm128<true><<<dim3(NT[0] / 128, 2), 256, 0, stream>>>(h1, w2t[0], c_b2[0], X1, NT[0], 256,
                                                            256);

    // ---- layer 1 (x: X1 f16, din=256) ----
    gather256<<<NT[1] / 4, 256, 0, stream>>>(X1, deg_l[1], adj_l[1], h0);
    gemm128<false><<<dim3(NT[1] / 128, 2), 256, 0, stream>>>(h0, w1t[1], c_b1[1], h1, NT[1], 256,
                                                             256);
    bn_mid(c_g[1], c_be[1], NT[1]);
    gemm128<true><<<dim3(NT[1] / 128, 2), 256, 0, stream>>>(h1, w2t[1], c_b2[1], X2, NT[1], 256,
                                                            256);

    // ---- layer 2 (x: X2 f16, din=256, M=1024 -> 64x64 gemm) ----
    gather256<<<NT[2] / 4, 256, 0, stream>>>(X2, deg_l[2], adj_l[2], h0);
    gemm_bt<false><<<dim3(NT[2] / 64, 4), 256, 0, stream>>>(h0, w1t[2], c_b1[2], h1, NT[2], 256,
                                                            256);
    bn_mid(c_g[2], c_be[2], NT[2]);
    gemm_bt<true><<<dim3(NT[2] / 64, 4), 256, 0, stream>>>(h1, w2t[2], c_b2[2], X3, NT[2], 256,
                                                           256);

    // ---- head ----
    gemm_bt<true><<<dim3(16, 4), 256, 0, stream>>>(X3, lin1t, lin1_b, T, 1024, 256, 256);
    head2<<<1024, 64, 0, stream>>>(T, lin2t_, lin2_b, out, 1024);
}

// Round 3
// 1191.496 us; speedup vs baseline: 1.2247x; 1.0924x over previous
//
#include <hip/hip_runtime.h>
#include <cmath>

typedef _Float16 f16;
typedef _Float16 half8 __attribute__((ext_vector_type(8)));
typedef _Float16 half4 __attribute__((ext_vector_type(4)));
typedef float f32x4 __attribute__((ext_vector_type(4)));

__device__ __forceinline__ void atomAddF(float* p, float v) { unsafeAtomicAdd(p, v); }

// async global->LDS, 16B per lane. LDS dest must be wave-uniform base + lane*16 (linear).
__device__ __forceinline__ void gload16(const void* g, void* l) {
    __builtin_amdgcn_global_load_lds((const __attribute__((address_space(1))) void*)g,
                                     (__attribute__((address_space(3))) void*)l, 16, 0, 0);
}

// ---------------- merged setup ----------------
// regions: w1t0 transpose | 6x 256x256 transposes | lin2 transpose | stats zero | deg zero
struct SetupP {
    const float* ws[7];
    f16* wd[7];
    const float* l2s;
    float* l2d;
    float* stats;  // 1536 floats (3 layers x (colsum[256], colsumsq[256]))
    int* deg;      // 136192 ints
};

__global__ void setup_all(SetupP p) {
    int i = blockIdx.x * 256 + threadIdx.x;
    if (i < 32768) {
        int k = i >> 8, n = i & 255;
        p.wd[0][(size_t)n * 128 + k] = (f16)p.ws[0][i];
        return;
    }
    i -= 32768;
    if (i < 6 * 65536) {
        int m = i >> 16, r = i & 65535;
        int k = r >> 8, n = r & 255;
        p.wd[1 + m][(size_t)n * 256 + k] = (f16)p.ws[1 + m][r];
        return;
    }
    i -= 6 * 65536;
    if (i < 12032) {
        int k = i / 47, j = i - k * 47;
        p.l2d[(size_t)j * 256 + k] = p.l2s[i];
        return;
    }
    i -= 12032;
    if (i < 1536) {
        p.stats[i] = 0.f;
        return;
    }
    i -= 1536;
    if (i < 136192) p.deg[i] = 0;
}

// ---------------- adjacency build, all 3 layers in one dispatch ----------------
__global__ void fill_all(const int* __restrict__ e0, const int* __restrict__ e1,
                         const int* __restrict__ e2, int E0, int E1, int E2, int* __restrict__ deg,
                         int* __restrict__ adj) {
    int e = blockIdx.x * 256 + threadIdx.x;
    const int *src, *tgt;
    int* d;
    int* a;
    if (e < E0) {
        src = e0; tgt = e0 + E0; d = deg; a = adj;
    } else if (e < E0 + E1) {
        e -= E0;
        src = e1; tgt = e1 + E1; d = deg + 123904; a = adj + (size_t)123904 * 64;
    } else if (e < E0 + E1 + E2) {
        e -= E0 + E1;
        src = e2; tgt = e2 + E2; d = deg + 135168; a = adj + (size_t)135168 * 64;
    } else {
        return;
    }
    int t = tgt[e];
    int pos = atomicAdd(&d[t], 1);
    if (pos < 64) a[(size_t)t * 64 + pos] = src[e];
}

// ---------------- gathers: h[t] = x[t] + sum_{s in adj[t]} x[s], one wave per row ----------------

// layer 0: x fp32 (1362944 x 128 -- full source table!), h f16 (123904 x 128)
__global__ void gather128(const float* __restrict__ x, const int* __restrict__ deg,
                          const int* __restrict__ adj, f16* __restrict__ h) {
    const int wave = threadIdx.x >> 6, lane = threadIdx.x & 63;
    const int row = blockIdx.x * 4 + wave;
    const int c = lane * 2;
    const float* xr = x + (size_t)row * 128 + c;
    float a0 = xr[0], a1 = xr[1];
    const int n = min(deg[row], 64);
    const int myadj = adj[(size_t)row * 64 + lane];
    int j = 0;
    for (; j + 4 <= n; j += 4) {
        int s0 = __shfl(myadj, j), s1 = __shfl(myadj, j + 1);
        int s2 = __shfl(myadj, j + 2), s3 = __shfl(myadj, j + 3);
        const float* p0 = x + (size_t)s0 * 128 + c;
        const float* p1 = x + (size_t)s1 * 128 + c;
        const float* p2 = x + (size_t)s2 * 128 + c;
        const float* p3 = x + (size_t)s3 * 128 + c;
        float b00 = p0[0], b01 = p0[1], b10 = p1[0], b11 = p1[1];
        float b20 = p2[0], b21 = p2[1], b30 = p3[0], b31 = p3[1];
        a0 += (b00 + b10) + (b20 + b30);
        a1 += (b01 + b11) + (b21 + b31);
    }
    for (; j < n; ++j) {
        int s = __shfl(myadj, j);
        const float* p = x + (size_t)s * 128 + c;
        a0 += p[0];
        a1 += p[1];
    }
    f16* hp = h + (size_t)row * 128 + c;
    hp[0] = (f16)a0;
    hp[1] = (f16)a1;
}

__global__ void gather256(const f16* __restrict__ x, const int* __restrict__ deg,
                          const int* __restrict__ adj, f16* __restrict__ h) {
    const int wave = threadIdx.x >> 6, lane = threadIdx.x & 63;
    const int row = blockIdx.x * 4 + wave;
    const int c = lane * 4;
    half4 xv = *(const half4*)(x + (size_t)row * 256 + c);
    float a0 = (float)xv[0], a1 = (float)xv[1], a2 = (float)xv[2], a3 = (float)xv[3];
    const int n = min(deg[row], 64);
    const int myadj = adj[(size_t)row * 64 + lane];
    int j = 0;
    for (; j + 4 <= n; j += 4) {
        int s0 = __shfl(myadj, j), s1 = __shfl(myadj, j + 1);
        int s2 = __shfl(myadj, j + 2), s3 = __shfl(myadj, j + 3);
        half4 v0 = *(const half4*)(x + (size_t)s0 * 256 + c);
        half4 v1 = *(const half4*)(x + (size_t)s1 * 256 + c);
        half4 v2 = *(const half4*)(x + (size_t)s2 * 256 + c);
        half4 v3 = *(const half4*)(x + (size_t)s3 * 256 + c);
        a0 += ((float)v0[0] + (float)v1[0]) + ((float)v2[0] + (float)v3[0]);
        a1 += ((float)v0[1] + (float)v1[1]) + ((float)v2[1] + (float)v3[1]);
        a2 += ((float)v0[2] + (float)v1[2]) + ((float)v2[2] + (float)v3[2]);
        a3 += ((float)v0[3] + (float)v1[3]) + ((float)v2[3] + (float)v3[3]);
    }
    for (; j < n; ++j) {
        int s = __shfl(myadj, j);
        half4 v = *(const half4*)(x + (size_t)s * 256 + c);
        a0 += (float)v[0];
        a1 += (float)v[1];
        a2 += (float)v[2];
        a3 += (float)v[3];
    }
    half4 o;
    o[0] = (f16)a0;
    o[1] = (f16)a1;
    o[2] = (f16)a2;
    o[3] = (f16)a3;
    *(half4*)(h + (size_t)row * 256 + c) = o;
}

// ---------------- gemm1: C = A @ Bt^T + bias (no relu), fused per-column stats ----------------
// 128x128 tile, global_load_lds(16B), chunk-XOR swizzle (LDS chunk p at row r = global chunk
// p^((r>>1)&3)). Epilogue: col partial sums/sumsq from fp32 acc -> LDS -> global atomics.
__global__ __launch_bounds__(256) void gemm128_stats(const f16* __restrict__ A,
                                                     const f16* __restrict__ Bt,
                                                     const float* __restrict__ bias,
                                                     f16* __restrict__ C,
                                                     float* __restrict__ colsum,
                                                     float* __restrict__ colsumsq, int M, int N,
                                                     int K) {
    __shared__ __attribute__((aligned(16))) f16 sA[128 * 32];
    __shared__ __attribute__((aligned(16))) f16 sB[128 * 32];
    __shared__ float ssum[128], ssq[128];
    const int tid = threadIdx.x;
    const int wave = tid >> 6, lane = tid & 63;
    const int quad = lane >> 4, l16 = lane & 15;
    const int wr = (wave & 1) * 64, wc = (wave >> 1) * 64;
    const int row0 = blockIdx.x * 128, col0 = blockIdx.y * 128;

    if (tid < 128)
        ssum[tid] = 0.f;
    else
        ssq[tid - 128] = 0.f;

    const int i0 = tid, i1 = tid + 256;
    const int r0s = i0 >> 2, c0s = (i0 & 3) ^ ((r0s >> 1) & 3);
    const int r1s = i1 >> 2, c1s = (i1 & 3) ^ ((r1s >> 1) & 3);
    const f16* ga0 = A + (size_t)(row0 + r0s) * K + c0s * 8;
    const f16* ga1 = A + (size_t)(row0 + r1s) * K + c1s * 8;
    const f16* gb0 = Bt + (size_t)(col0 + r0s) * K + c0s * 8;
    const f16* gb1 = Bt + (size_t)(col0 + r1s) * K + c1s * 8;
    f16* la0 = &sA[i0 * 8];
    f16* la1 = &sA[i1 * 8];
    f16* lb0 = &sB[i0 * 8];
    f16* lb1 = &sB[i1 * 8];

    f32x4 acc[4][4] = {};

    for (int k0 = 0; k0 < K; k0 += 32) {
        __syncthreads();
        gload16(ga0 + k0, la0);
        gload16(ga1 + k0, la1);
        gload16(gb0 + k0, lb0);
        gload16(gb1 + k0, lb1);
        __syncthreads();
        half8 af[4], bf[4];
#pragma unroll
        for (int r = 0; r < 4; ++r) {
            const int ar = wr + r * 16 + l16;
            af[r] = *(const half8*)&sA[ar * 32 + ((quad ^ ((ar >> 1) & 3)) * 8)];
        }
#pragma unroll
        for (int c = 0; c < 4; ++c) {
            const int br = wc + c * 16 + l16;
            bf[c] = *(const half8*)&sB[br * 32 + ((quad ^ ((br >> 1) & 3)) * 8)];
        }
#pragma unroll
        for (int r = 0; r < 4; ++r)
#pragma unroll
            for (int c = 0; c < 4; ++c)
                acc[r][c] = __builtin_amdgcn_mfma_f32_16x16x32_f16(af[r], bf[c], acc[r][c], 0, 0, 0);
    }

    // epilogue: store + per-column stats. C/D layout: col = l16, row = quad*4 + reg.
#pragma unroll
    for (int c = 0; c < 4; ++c) {
        const int lcol = wc + c * 16 + l16;
        const int gcol = col0 + lcol;
        const float b = bias[gcol];
        float cs = 0.f, cq = 0.f;
#pragma unroll
        for (int r = 0; r < 4; ++r) {
#pragma unroll
            for (int i = 0; i < 4; ++i) {
                const int grow = row0 + wr + r * 16 + quad * 4 + i;
                float v = acc[r][c][i] + b;
                C[(size_t)grow * N + gcol] = (f16)v;
                cs += v;
                cq += v * v;
            }
        }
        // combine the 4 quads (same column) via butterfly over lane bits 4,5
        cs += __shfl_xor(cs, 16);
        cs += __shfl_xor(cs, 32);
        cq += __shfl_xor(cq, 16);
        cq += __shfl_xor(cq, 32);
        if (quad == 0) {
            atomicAdd(&ssum[lcol], cs);
            atomicAdd(&ssq[lcol], cq);
        }
    }
    __syncthreads();
    if (tid < 128)
        atomAddF(&colsum[col0 + tid], ssum[tid]);
    else
        atomAddF(&colsumsq[col0 + tid - 128], ssq[tid - 128]);
}

// ---------------- gemm2: C = relu( relu(BN(A)) @ Bt^T + bias ) ----------------
// BN scale/shift computed in-block from stats (complete by stream order); applied + relu'd
// during A reg-staging (global->reg->transform->swizzled ds_write). B: global_load_lds. K=256.
__global__ __launch_bounds__(256) void gemm128_bn(const f16* __restrict__ A,
                                                  const f16* __restrict__ Bt,
                                                  const float* __restrict__ bias,
                                                  const float* __restrict__ colsum,
                                                  const float* __restrict__ colsumsq,
                                                  const float* __restrict__ g,
                                                  const float* __restrict__ be, float nt_inv,
                                                  f16* __restrict__ C, int M, int N, int K) {
    __shared__ __attribute__((aligned(16))) f16 sA[128 * 32];
    __shared__ __attribute__((aligned(16))) f16 sB[128 * 32];
    __shared__ float s_scale[256], s_shift[256];
    const int tid = threadIdx.x;
    const int wave = tid >> 6, lane = tid & 63;
    const int quad = lane >> 4, l16 = lane & 15;
    const int wr = (wave & 1) * 64, wc = (wave >> 1) * 64;
    const int row0 = blockIdx.x * 128, col0 = blockIdx.y * 128;

    {  // BN finalize, per block
        float mu = colsum[tid] * nt_inv;
        float var = colsumsq[tid] * nt_inv - mu * mu;
        float sc = g[tid] * rsqrtf(var + 1e-5f);
        s_scale[tid] = sc;
        s_shift[tid] = be[tid] - mu * sc;
    }
    __syncthreads();

    const int i0 = tid, i1 = tid + 256;
    const int r0s = i0 >> 2, c0s = (i0 & 3) ^ ((r0s >> 1) & 3);
    const int r1s = i1 >> 2, c1s = (i1 & 3) ^ ((r1s >> 1) & 3);
    const f16* ga0 = A + (size_t)(row0 + r0s) * K + c0s * 8;
    const f16* ga1 = A + (size_t)(row0 + r1s) * K + c1s * 8;
    const f16* gb0 = Bt + (size_t)(col0 + r0s) * K + c0s * 8;
    const f16* gb1 = Bt + (size_t)(col0 + r1s) * K + c1s * 8;
    f16* la0 = &sA[i0 * 8];
    f16* la1 = &sA[i1 * 8];
    f16* lb0 = &sB[i0 * 8];
    f16* lb1 = &sB[i1 * 8];

    f32x4 acc[4][4] = {};

    for (int k0 = 0; k0 < K; k0 += 32) {
        // A: load + BN+relu in registers (reads only global + stable s_scale)
        half8 va0 = *(const half8*)(ga0 + k0);
        half8 va1 = *(const half8*)(ga1 + k0);
        half8 ta0, ta1;
        const int kb0 = k0 + c0s * 8, kb1 = k0 + c1s * 8;
#pragma unroll
        for (int j = 0; j < 8; ++j) {
            float f0 = (float)va0[j] * s_scale[kb0 + j] + s_shift[kb0 + j];
            ta0[j] = (f16)fmaxf(f0, 0.f);
            float f1 = (float)va1[j] * s_scale[kb1 + j] + s_shift[kb1 + j];
            ta1[j] = (f16)fmaxf(f1, 0.f);
        }
        __syncthreads();  // prior iteration's frag reads done before overwrite
        gload16(gb0 + k0, lb0);
        gload16(gb1 + k0, lb1);
        *(half8*)la0 = ta0;
        *(half8*)la1 = ta1;
        __syncthreads();  // drains vmcnt + lgkmcnt: tile visible
        half8 af[4], bf[4];
#pragma unroll
        for (int r = 0; r < 4; ++r) {
            const int ar = wr + r * 16 + l16;
            af[r] = *(const half8*)&sA[ar * 32 + ((quad ^ ((ar >> 1) & 3)) * 8)];
        }
#pragma unroll
        for (int c = 0; c < 4; ++c) {
            const int br = wc + c * 16 + l16;
            bf[c] = *(const half8*)&sB[br * 32 + ((quad ^ ((br >> 1) & 3)) * 8)];
        }
#pragma unroll
        for (int r = 0; r < 4; ++r)
#pragma unroll
            for (int c = 0; c < 4; ++c)
                acc[r][c] = __builtin_amdgcn_mfma_f32_16x16x32_f16(af[r], bf[c], acc[r][c], 0, 0, 0);
    }

#pragma unroll
    for (int c = 0; c < 4; ++c) {
        const int gcol = col0 + wc + c * 16 + l16;
        const float b = bias[gcol];
#pragma unroll
        for (int r = 0; r < 4; ++r) {
#pragma unroll
            for (int i = 0; i < 4; ++i) {
                const int grow = row0 + wr + r * 16 + quad * 4 + i;
                float v = fmaxf(acc[r][c][i] + b, 0.f);
                C[(size_t)grow * N + gcol] = (f16)v;
            }
        }
    }
}

// ---------------- 64x64 GEMM (head lin1) ----------------
template <bool RELU>
__global__ __launch_bounds__(256) void gemm_bt(const f16* __restrict__ A, const f16* __restrict__ Bt,
                                               const float* __restrict__ bias, f16* __restrict__ C,
                                               int M, int N, int K) {
    constexpr int BM = 64, BN = 64, BK = 32, LP = 40;
    __shared__ f16 sA[BM * LP];
    __shared__ f16 sB[BN * LP];
    const int tid = threadIdx.x;
    const int wave = tid >> 6, lane = tid & 63;
    const int quad = lane >> 4, l16 = lane & 15;
    const int wr = (wave & 1) * 32, wc = (wave >> 1) * 32;
    const int row0 = blockIdx.x * BM, col0 = blockIdx.y * BN;
    const int srow = tid >> 2, soff = (tid & 3) * 8;

    f32x4 acc[2][2] = {};

    for (int k0 = 0; k0 < K; k0 += BK) {
        __syncthreads();
        *(half8*)&sA[srow * LP + soff] =
            *(const half8*)(A + (size_t)(row0 + srow) * K + (k0 + soff));
        *(half8*)&sB[srow * LP + soff] =
            *(const half8*)(Bt + (size_t)(col0 + srow) * K + (k0 + soff));
        __syncthreads();
        half8 af[2], bf[2];
#pragma unroll
        for (int r = 0; r < 2; ++r) af[r] = *(const half8*)&sA[(wr + r * 16 + l16) * LP + quad * 8];
#pragma unroll
        for (int c = 0; c < 2; ++c) bf[c] = *(const half8*)&sB[(wc + c * 16 + l16) * LP + quad * 8];
#pragma unroll
        for (int r = 0; r < 2; ++r)
#pragma unroll
            for (int c = 0; c < 2; ++c)
                acc[r][c] = __builtin_amdgcn_mfma_f32_16x16x32_f16(af[r], bf[c], acc[r][c], 0, 0, 0);
    }

#pragma unroll
    for (int c = 0; c < 2; ++c) {
        const int gcol = col0 + wc + c * 16 + l16;
        const float b = bias[gcol];
#pragma unroll
        for (int r = 0; r < 2; ++r) {
#pragma unroll
            for (int i = 0; i < 4; ++i) {
                const int grow = row0 + wr + r * 16 + quad * 4 + i;
                float v = acc[r][c][i] + b;
                if (RELU) v = fmaxf(v, 0.f);
                C[(size_t)grow * N + gcol] = (f16)v;
            }
        }
    }
}

// ---------------- head: logits + log_softmax ----------------
__global__ void head2(const f16* __restrict__ T, const float* __restrict__ w2t,
                      const float* __restrict__ b2, float* __restrict__ out, int rows) {
    const int row = blockIdx.x;
    const int lane = threadIdx.x;
    __shared__ float tr[256];
    for (int i = lane; i < 256; i += 64) tr[i] = (float)T[(size_t)row * 256 + i];
    __syncthreads();
    float d = -1e30f;
    if (lane < 47) {
        const float* wr = w2t + (size_t)lane * 256;
        float dot = 0.f;
        for (int k = 0; k < 256; k += 4) {
            dot += tr[k] * wr[k] + tr[k + 1] * wr[k + 1] + tr[k + 2] * wr[k + 2] +
                   tr[k + 3] * wr[k + 3];
        }
        d = dot + b2[lane];
    }
    float m = d;
    for (int off = 32; off; off >>= 1) m = fmaxf(m, __shfl_xor(m, off));
    float e = (lane < 47) ? expf(d - m) : 0.f;
    float s = e;
    for (int off = 32; off; off >>= 1) s += __shfl_xor(s, off);
    if (lane < 47) out[(size_t)row * 47 + lane] = d - m - logf(s);
}

// ---------------- launch ----------------

extern "C" void kernel_launch(void* const* d_in, const int* in_sizes, int n_in, void* d_out,
                              int out_size, void* d_ws, size_t ws_size, hipStream_t stream) {
    const float* x0 = (const float*)d_in[0];
    const int* ei[3] = {(const int*)d_in[1], (const int*)d_in[2], (const int*)d_in[3]};
    const int E[3] = {in_sizes[1] / 2, in_sizes[2] / 2, in_sizes[3] / 2};
    const float* c_w1[3] = {(const float*)d_in[4], (const float*)d_in[10], (const float*)d_in[16]};
    const float* c_b1[3] = {(const float*)d_in[5], (const float*)d_in[11], (const float*)d_in[17]};
    const float* c_g[3] = {(const float*)d_in[6], (const float*)d_in[12], (const float*)d_in[18]};
    const float* c_be[3] = {(const float*)d_in[7], (const float*)d_in[13], (const float*)d_in[19]};
    const float* c_w2[3] = {(const float*)d_in[8], (const float*)d_in[14], (const float*)d_in[20]};
    const float* c_b2[3] = {(const float*)d_in[9], (const float*)d_in[15], (const float*)d_in[21]};
    const float* lin1_w = (const float*)d_in[22];
    const float* lin1_b = (const float*)d_in[23];
    const float* lin2_w = (const float*)d_in[24];
    const float* lin2_b = (const float*)d_in[25];
    float* out = (float*)d_out;

    const int NT[3] = {123904, 11264, 1024};

    char* base = (char*)d_ws;
    size_t off = 0;
    auto take = [&](size_t bytes) -> char* {
        char* p = base + off;
        off = (off + bytes + 255) & ~(size_t)255;
        return p;
    };
    f16* w1t[3];
    w1t[0] = (f16*)take((size_t)256 * 128 * sizeof(f16));
    w1t[1] = (f16*)take((size_t)256 * 256 * sizeof(f16));
    w1t[2] = (f16*)take((size_t)256 * 256 * sizeof(f16));
    f16* w2t[3];
    for (int i = 0; i < 3; ++i) w2t[i] = (f16*)take((size_t)256 * 256 * sizeof(f16));
    f16* lin1t = (f16*)take((size_t)256 * 256 * sizeof(f16));
    float* lin2t_ = (float*)take((size_t)47 * 256 * sizeof(float));
    float* stats = (float*)take(3 * 512 * sizeof(float));
    int* deg = (int*)take((size_t)136192 * sizeof(int));
    int* adj = (int*)take((size_t)136192 * 64 * sizeof(int));
    f16* h0 = (f16*)take((size_t)123904 * 128 * sizeof(f16));  // also holds 11264x256, 1024x256
    f16* h1 = (f16*)take((size_t)123904 * 256 * sizeof(f16));
    f16* X1 = (f16*)take((size_t)123904 * 256 * sizeof(f16));
    f16* X2 = (f16*)take((size_t)11264 * 256 * sizeof(f16));
    f16* X3 = (f16*)take((size_t)1024 * 256 * sizeof(f16));
    f16* T = (f16*)take((size_t)1024 * 256 * sizeof(f16));
    (void)ws_size;
    (void)out_size;
    (void)n_in;

    int* deg_l[3] = {deg, deg + 123904, deg + 135168};
    int* adj_l[3] = {adj, adj + (size_t)123904 * 64, adj + (size_t)135168 * 64};
    float* cs_l[3] = {stats, stats + 512, stats + 1024};  // colsum[256] | colsumsq[256]

    // merged setup (575744 work items = 2249 blocks)
    SetupP sp;
    sp.ws[0] = c_w1[0];
    sp.ws[1] = c_w1[1];
    sp.ws[2] = c_w1[2];
    sp.ws[3] = c_w2[0];
    sp.ws[4] = c_w2[1];
    sp.ws[5] = c_w2[2];
    sp.ws[6] = lin1_w;
    sp.wd[0] = w1t[0];
    sp.wd[1] = w1t[1];
    sp.wd[2] = w1t[2];
    sp.wd[3] = w2t[0];
    sp.wd[4] = w2t[1];
    sp.wd[5] = w2t[2];
    sp.wd[6] = lin1t;
    sp.l2s = lin2_w;
    sp.l2d = lin2t_;
    sp.stats = stats;
    sp.deg = deg;
    setup_all<<<2249, 256, 0, stream>>>(sp);

    fill_all<<<(E[0] + E[1] + E[2] + 255) / 256, 256, 0, stream>>>(ei[0], ei[1], ei[2], E[0], E[1],
                                                                  E[2], deg, adj);

    // ---- layer 0 (din=128; x0 is 1362944x128 fp32 -- sources span the FULL table) ----
    gather128<<<NT[0] / 4, 256, 0, stream>>>(x0, deg_l[0], adj_l[0], h0);
    gemm128_stats<<<dim3(NT[0] / 128, 2), 256, 0, stream>>>(h0, w1t[0], c_b1[0], h1, cs_l[0],
                                                            cs_l[0] + 256, NT[0], 256, 128);
    gemm128_bn<<<dim3(NT[0] / 128, 2), 256, 0, stream>>>(h1, w2t[0], c_b2[0], cs_l[0],
                                                         cs_l[0] + 256, c_g[0], c_be[0],
                                                         1.0f / NT[0], X1, NT[0], 256, 256);

    // ---- layer 1 (din=256) ----
    gather256<<<NT[1] / 4, 256, 0, stream>>>(X1, deg_l[1], adj_l[1], h0);
    gemm128_stats<<<dim3(NT[1] / 128, 2), 256, 0, stream>>>(h0, w1t[1], c_b1[1], h1, cs_l[1],
                                                            cs_l[1] + 256, NT[1], 256, 256);
    gemm128_bn<<<dim3(NT[1] / 128, 2), 256, 0, stream>>>(h1, w2t[1], c_b2[1], cs_l[1],
                                                         cs_l[1] + 256, c_g[1], c_be[1],
                                                         1.0f / NT[1], X2, NT[1], 256, 256);

    // ---- layer 2 (din=256) ----
    gather256<<<NT[2] / 4, 256, 0, stream>>>(X2, deg_l[2], adj_l[2], h0);
    gemm128_stats<<<dim3(NT[2] / 128, 2), 256, 0, stream>>>(h0, w1t[2], c_b1[2], h1, cs_l[2],
                                                            cs_l[2] + 256, NT[2], 256, 256);
    gemm128_bn<<<dim3(NT[2] / 128, 2), 256, 0, stream>>>(h1, w2t[2], c_b2[2], cs_l[2],
                                                         cs_l[2] + 256, c_g[2], c_be[2],
                                                         1.0f / NT[2], X3, NT[2], 256, 256);

    // ---- head ----
    gemm_bt<true><<<dim3(16, 4), 256, 0, stream>>>(X3, lin1t, lin1_b, T, 1024, 256, 256);
    head2<<<1024, 64, 0, stream>>>(T, lin2t_, lin2_b, out, 1024);
}